// Round 14
// baseline (409.660 us; speedup 1.0000x reference)
//
#include <hip/hip_runtime.h>
#include <hip/hip_bf16.h>
#include <hip/hip_fp16.h>
#include <cstdint>

#define IN_DIM 128
#define OUT_DIM 64
#define FEATD 50
#define NEG_SLOPE 0.01f
#define NCH 8  // = number of XCDs; blockIdx%8 -> XCD (empirical round-robin)

typedef unsigned int uint32;
typedef _Float16 half4 __attribute__((ext_vector_type(4)));
typedef float f32x4 __attribute__((ext_vector_type(4)));

// K0: zero cnt[n_sents*NCH]; block 0 computes v3.
__global__ __launch_bounds__(256) void k_init(const float* __restrict__ W_feat,
                                              const float* __restrict__ W_attn,
                                              float* __restrict__ v3,
                                              uint32* __restrict__ cnt,
                                              int ncnt) {
  int i = blockIdx.x * 256 + threadIdx.x;
  if (i < ncnt) cnt[i] = 0u;
  if (blockIdx.x == 0 && threadIdx.x < FEATD) {
    int j = threadIdx.x;
    float s = 0.f;
    #pragma unroll
    for (int o = 0; o < OUT_DIM; ++o)
      s = fmaf(W_attn[2 * OUT_DIM + o], W_feat[o * FEATD + j], s);
    v3[j] = s;
  }
}

// K1: node GEMM on matrix cores (frozen since round 5).
__global__ __launch_bounds__(256) void k_node_mfma(const float* __restrict__ h,
    const float* __restrict__ W_fc, const float* __restrict__ W_attn,
    __half* __restrict__ z, float* __restrict__ s1, float* __restrict__ s2,
    int n_words, int n_nodes) {
  __shared__ float zl[4][16][68];
  int w = threadIdx.x >> 6, lane = threadIdx.x & 63;
  int nb = blockIdx.x * 64 + w * 16;
  int lrow = lane & 15;
  int lk4 = (lane >> 4) * 4;

  int an = nb + lrow;
  if (an >= n_nodes) an = n_nodes - 1;
  const float* hrow = h + (size_t)an * IN_DIM;

  f32x4 acc[4];
  #pragma unroll
  for (int nt = 0; nt < 4; ++nt) acc[nt] = (f32x4){0.f, 0.f, 0.f, 0.f};

  #pragma unroll
  for (int ks = 0; ks < 8; ++ks) {
    float4 hv = *(const float4*)(hrow + ks * 16 + lk4);
    half4 a;
    a[0] = (_Float16)hv.x; a[1] = (_Float16)hv.y;
    a[2] = (_Float16)hv.z; a[3] = (_Float16)hv.w;
    #pragma unroll
    for (int nt = 0; nt < 4; ++nt) {
      const float* wrow = W_fc + (size_t)(nt * 16 + lrow) * IN_DIM + ks * 16 + lk4;
      float4 wv = *(const float4*)wrow;
      half4 b;
      b[0] = (_Float16)wv.x; b[1] = (_Float16)wv.y;
      b[2] = (_Float16)wv.z; b[3] = (_Float16)wv.w;
      acc[nt] = __builtin_amdgcn_mfma_f32_16x16x16f16(a, b, acc[nt], 0, 0, 0);
    }
  }

  int drow = (lane >> 4) * 4;
  #pragma unroll
  for (int nt = 0; nt < 4; ++nt)
    #pragma unroll
    for (int r = 0; r < 4; ++r)
      zl[w][drow + r][nt * 16 + lrow] = acc[nt][r];

  int node = lane >> 2;
  int chunk = lane & 3;
  float v[16];
  #pragma unroll
  for (int q = 0; q < 4; ++q) {
    float4 t = *(const float4*)&zl[w][node][chunk * 16 + q * 4];
    v[4 * q + 0] = t.x; v[4 * q + 1] = t.y;
    v[4 * q + 2] = t.z; v[4 * q + 3] = t.w;
  }

  int gn = nb + node;
  bool valid = gn < n_nodes;
  bool isword = gn < n_words;
  const float* wa = W_attn + (isword ? 0 : OUT_DIM) + chunk * 16;
  float p = 0.f;
  #pragma unroll
  for (int t = 0; t < 16; ++t) p = fmaf(v[t], wa[t], p);
  p += __shfl_xor(p, 1);
  p += __shfl_xor(p, 2);

  if (valid && chunk == 0) {
    if (isword) s1[gn] = p; else s2[gn - n_words] = p;
  }
  if (valid && isword) {
    uint32 d[8];
    #pragma unroll
    for (int k = 0; k < 8; ++k) {
      __half2 t = __floats2half2_rn(v[2 * k], v[2 * k + 1]);
      d[k] = *(uint32*)&t;
    }
    uint4* dstp = (uint4*)(z + (size_t)gn * OUT_DIM + chunk * 16);
    dstp[0] = make_uint4(d[0], d[1], d[2], d[3]);
    dstp[1] = make_uint4(d[4], d[5], d[6], d[7]);
  }
}

// K2: histogram over (dst, src-chunk) + per-edge rank; 2 edges/thread.
__global__ __launch_bounds__(256) void k_hist(const int* __restrict__ dst,
                                              const int* __restrict__ src,
                                              uint32* __restrict__ cnt,
                                              uint32* __restrict__ rank,
                                              int E, uint32 cw) {
  int i = blockIdx.x * 256 + threadIdx.x;
  int e0 = i * 2;
  if (e0 + 1 < E) {
    int2 d2 = *(const int2*)(dst + e0);
    int2 s2 = *(const int2*)(src + e0);
    uint32 c0 = (uint32)s2.x / cw, c1 = (uint32)s2.y / cw;
    uint32 r0 = atomicAdd(&cnt[(uint32)d2.x * NCH + c0], 1u);
    uint32 r1 = atomicAdd(&cnt[(uint32)d2.y * NCH + c1], 1u);
    *(uint2*)(rank + e0) = make_uint2(r0, r1);
  } else if (e0 < E) {
    uint32 c0 = (uint32)src[e0] / cw;
    rank[e0] = atomicAdd(&cnt[(uint32)dst[e0] * NCH + c0], 1u);
  }
}

// K3a/b/c: two-level multi-block exclusive scan (coalesced).
__global__ __launch_bounds__(1024) void k_scanA(const uint32* __restrict__ cnt,
    uint32* __restrict__ off, uint32* __restrict__ btot, int n) {
  __shared__ uint32 part[1024];
  int t = threadIdx.x;
  int i = blockIdx.x * 1024 + t;
  uint32 v = (i < n) ? cnt[i] : 0u;
  part[t] = v;
  __syncthreads();
  uint32 x = v;
  for (int d = 1; d < 1024; d <<= 1) {
    uint32 y = (t >= d) ? part[t - d] : 0u;
    __syncthreads();
    x += y;
    part[t] = x;
    __syncthreads();
  }
  if (i < n) off[i] = x - v;          // exclusive within block
  if (t == 1023) btot[blockIdx.x] = x;
}
__global__ __launch_bounds__(1024) void k_scanB(const uint32* __restrict__ btot,
                                                uint32* __restrict__ boff, int nb) {
  __shared__ uint32 part[1024];
  int t = threadIdx.x;
  uint32 v = (t < nb) ? btot[t] : 0u;
  part[t] = v;
  __syncthreads();
  uint32 x = v;
  for (int d = 1; d < 1024; d <<= 1) {
    uint32 y = (t >= d) ? part[t - d] : 0u;
    __syncthreads();
    x += y;
    part[t] = x;
    __syncthreads();
  }
  if (t < nb) boff[t] = x - v;
  if (t == 1023) boff[nb] = x;        // grand total
}
__global__ __launch_bounds__(1024) void k_scanC(uint32* __restrict__ off,
    const uint32* __restrict__ boff, int n, int nb) {
  int i = blockIdx.x * 1024 + threadIdx.x;
  if (i < n) off[i] += boff[i >> 10];
  if (i == 0) off[n] = boff[nb];
}

// K4: per edge: f = tfidf.v3 ; e = leaky(...); store {exp(e), src} at
// off[dst*NCH + chunk(src)] + rank (dst-major, chunk-grouped).
__global__ __launch_bounds__(256) void k_edge(const float* __restrict__ tfidf,
    const int* __restrict__ src, const int* __restrict__ dst,
    const float* __restrict__ s1, const float* __restrict__ s2,
    const float* __restrict__ v3, const uint32* __restrict__ off,
    const uint32* __restrict__ rank, float2* __restrict__ pair, int E,
    uint32 cw) {
  int e = blockIdx.x * 256 + threadIdx.x;
  if (e >= E) return;
  const float* row = tfidf + (size_t)e * FEATD;
  float f = 0.f;
  #pragma unroll
  for (int k = 0; k < FEATD / 2; ++k) {
    float2 v = *(const float2*)(row + 2 * k);
    f = fmaf(v.x, v3[2 * k], f);
    f = fmaf(v.y, v3[2 * k + 1], f);
  }
  int sidx = src[e], d = dst[e];
  float ev = s1[sidx] + s2[d] + f;
  ev = ev >= 0.f ? ev : NEG_SLOPE * ev;
  float exv = __expf(ev);
  float2 pr;
  pr.x = exv;
  pr.y = __int_as_float(sidx);
  uint32 c = (uint32)sidx / cw;
  pair[off[(uint32)d * NCH + c] + rank[e]] = pr;
}

// K5a: per-(sentence, chunk) partial sums. blockIdx = g*NCH + c, so c ==
// blockIdx % 8 == XCD id (round-robin assumption) -> each XCD's blocks gather
// ONLY from z-chunk c (3.2 MB, L2-resident). 4 waves = 4 sentences per block.
__global__ __launch_bounds__(256) void k_aggp(const __half* __restrict__ z,
    const float2* __restrict__ pair, const uint32* __restrict__ off,
    float* __restrict__ pout, float* __restrict__ psum, int n_sents) {
  int w = threadIdx.x >> 6, lane = threadIdx.x & 63;
  int c = blockIdx.x & (NCH - 1);
  int g = blockIdx.x / NCH;
  int s = g * 4 + w;
  if (s >= n_sents) return;
  int seg = s * NCH + c;
  uint32 j0 = off[seg], j1 = off[seg + 1];
  int sub = lane >> 4;       // 0..3: edge sub-stream
  int d4 = (lane & 15) * 4;  // dim base

  float a0 = 0.f, a1 = 0.f, a2 = 0.f, a3 = 0.f, sa = 0.f;
  uint32 b = j0;
  for (; b + 8 <= j1; b += 8) {
    float2 p0 = pair[b + sub];
    float2 p1 = pair[b + 4 + sub];
    uint2 u0 = *(const uint2*)(z + (size_t)(uint32)__float_as_int(p0.y) * OUT_DIM + d4);
    uint2 u1 = *(const uint2*)(z + (size_t)(uint32)__float_as_int(p1.y) * OUT_DIM + d4);
    __half2 h01 = *(__half2*)&u0.x, h23 = *(__half2*)&u0.y;
    a0 = fmaf(p0.x, __low2float(h01), a0);
    a1 = fmaf(p0.x, __high2float(h01), a1);
    a2 = fmaf(p0.x, __low2float(h23), a2);
    a3 = fmaf(p0.x, __high2float(h23), a3);
    sa += p0.x;
    __half2 g01 = *(__half2*)&u1.x, g23 = *(__half2*)&u1.y;
    a0 = fmaf(p1.x, __low2float(g01), a0);
    a1 = fmaf(p1.x, __high2float(g01), a1);
    a2 = fmaf(p1.x, __low2float(g23), a2);
    a3 = fmaf(p1.x, __high2float(g23), a3);
    sa += p1.x;
  }
  for (; b + 4 <= j1; b += 4) {
    float2 p = pair[b + sub];
    uint2 u = *(const uint2*)(z + (size_t)(uint32)__float_as_int(p.y) * OUT_DIM + d4);
    __half2 h01 = *(__half2*)&u.x, h23 = *(__half2*)&u.y;
    a0 = fmaf(p.x, __low2float(h01), a0);
    a1 = fmaf(p.x, __high2float(h01), a1);
    a2 = fmaf(p.x, __low2float(h23), a2);
    a3 = fmaf(p.x, __high2float(h23), a3);
    sa += p.x;
  }
  if (sub < (int)(j1 - b)) {
    float2 p = pair[b + sub];
    uint2 u = *(const uint2*)(z + (size_t)(uint32)__float_as_int(p.y) * OUT_DIM + d4);
    __half2 h01 = *(__half2*)&u.x, h23 = *(__half2*)&u.y;
    a0 = fmaf(p.x, __low2float(h01), a0);
    a1 = fmaf(p.x, __high2float(h01), a1);
    a2 = fmaf(p.x, __low2float(h23), a2);
    a3 = fmaf(p.x, __high2float(h23), a3);
    sa += p.x;
  }

  a0 += __shfl_xor(a0, 16); a0 += __shfl_xor(a0, 32);
  a1 += __shfl_xor(a1, 16); a1 += __shfl_xor(a1, 32);
  a2 += __shfl_xor(a2, 16); a2 += __shfl_xor(a2, 32);
  a3 += __shfl_xor(a3, 16); a3 += __shfl_xor(a3, 32);
  sa += __shfl_xor(sa, 16); sa += __shfl_xor(sa, 32);

  if (sub == 0) {
    float4 o;
    o.x = a0; o.y = a1; o.z = a2; o.w = a3;
    *(float4*)(pout + (size_t)seg * OUT_DIM + d4) = o;
    if (lane == 0) psum[seg] = sa;
  }
}

// K5b: combine 8 chunk-partials per sentence; divide; write out.
__global__ __launch_bounds__(256) void k_combine(const float* __restrict__ pout,
    const float* __restrict__ psum, float* __restrict__ out, int n_sents) {
  int w = threadIdx.x >> 6, lane = threadIdx.x & 63;
  int s = blockIdx.x * 4 + w;
  if (s >= n_sents) return;
  float acc = 0.f, sa = 0.f;
  #pragma unroll
  for (int c = 0; c < NCH; ++c) {
    acc += pout[((size_t)s * NCH + c) * OUT_DIM + lane];
    sa += psum[s * NCH + c];
  }
  out[(size_t)s * OUT_DIM + lane] = (sa > 0.f) ? (acc / sa) : 0.f;
}

extern "C" void kernel_launch(void* const* d_in, const int* in_sizes, int n_in,
                              void* d_out, int out_size, void* d_ws, size_t ws_size,
                              hipStream_t stream) {
  const float* h      = (const float*)d_in[0];
  const float* tfidf  = (const float*)d_in[1];
  const float* W_fc   = (const float*)d_in[2];
  const float* W_feat = (const float*)d_in[3];
  const float* W_attn = (const float*)d_in[4];
  const int*   src    = (const int*)d_in[5];
  const int*   dst    = (const int*)d_in[6];

  int n_nodes = in_sizes[0] / IN_DIM;   // 220000
  int E       = in_sizes[5];            // 2,000,000
  int n_sents = out_size / OUT_DIM;     // 20000
  int n_words = n_nodes - n_sents;      // 200000
  float* out = (float*)d_out;

  uint32 cw = (uint32)((n_words + NCH - 1) / NCH);  // 25000 words/chunk (3.2MB z)
  int ncnt = n_sents * NCH;                          // 160000
  int nb = (ncnt + 1023) / 1024;                     // 157 scan blocks

  char* ws = (char*)d_ws;
  size_t ofs = 0;
  auto alloc = [&](size_t bytes) -> char* {
    char* p = ws + ofs;
    ofs += (bytes + 255) / 256 * 256;
    return p;
  };
  __half* z      = (__half*)alloc((size_t)n_words * OUT_DIM * 2);
  float*  s1     = (float*)alloc((size_t)n_words * 4);
  float*  s2     = (float*)alloc((size_t)n_sents * 4);
  float2* pair   = (float2*)alloc((size_t)E * 8);
  uint32* rank   = (uint32*)alloc((size_t)E * 4);
  uint32* cnt    = (uint32*)alloc((size_t)ncnt * 4);
  uint32* offs   = (uint32*)alloc((size_t)(ncnt + 1) * 4);
  uint32* btot   = (uint32*)alloc(1028 * 4);
  uint32* boff   = (uint32*)alloc(1028 * 4);
  float*  pout   = (float*)alloc((size_t)ncnt * OUT_DIM * 4);  // 41 MB
  float*  psum   = (float*)alloc((size_t)ncnt * 4);
  float*  v3     = (float*)alloc(FEATD * 4);
  (void)ws_size; (void)n_in;

  k_init<<<(ncnt + 255) / 256, 256, 0, stream>>>(W_feat, W_attn, v3, cnt, ncnt);
  k_node_mfma<<<(n_nodes + 63) / 64, 256, 0, stream>>>(h, W_fc, W_attn, z, s1,
                                                       s2, n_words, n_nodes);
  k_hist<<<(E / 2 + 255) / 256, 256, 0, stream>>>(dst, src, cnt, rank, E, cw);
  k_scanA<<<nb, 1024, 0, stream>>>(cnt, offs, btot, ncnt);
  k_scanB<<<1, 1024, 0, stream>>>(btot, boff, nb);
  k_scanC<<<(ncnt + 1024) / 1024, 1024, 0, stream>>>(offs, boff, ncnt, nb);
  k_edge<<<(E + 255) / 256, 256, 0, stream>>>(tfidf, src, dst, s1, s2, v3,
                                              offs, rank, pair, E, cw);
  k_aggp<<<((n_sents + 3) / 4) * NCH, 256, 0, stream>>>(z, pair, offs, pout,
                                                        psum, n_sents);
  k_combine<<<(n_sents + 3) / 4, 256, 0, stream>>>(pout, psum, out, n_sents);
}

// Round 15
// 379.230 us; speedup vs baseline: 1.0802x; 1.0802x over previous
//
#include <hip/hip_runtime.h>
#include <hip/hip_bf16.h>
#include <hip/hip_fp16.h>
#include <cstdint>

#define IN_DIM 128
#define OUT_DIM 64
#define FEATD 50
#define NEG_SLOPE 0.01f

typedef unsigned int uint32;
typedef _Float16 half4 __attribute__((ext_vector_type(4)));
typedef float f32x4 __attribute__((ext_vector_type(4)));

// K0: v3[j] = sum_o W_attn[128+o] * W_feat[o*FEATD+j]  (block 0) + zero cnt
__global__ __launch_bounds__(256) void k_v3zero(const float* __restrict__ W_feat,
                                                const float* __restrict__ W_attn,
                                                float* __restrict__ v3,
                                                uint32* __restrict__ cnt,
                                                int n_sents) {
  int i = blockIdx.x * 256 + threadIdx.x;
  if (i < n_sents) cnt[i] = 0u;
  if (blockIdx.x == 0 && threadIdx.x < FEATD) {
    int j = threadIdx.x;
    float s = 0.f;
    #pragma unroll
    for (int o = 0; o < OUT_DIM; ++o)
      s = fmaf(W_attn[2 * OUT_DIM + o], W_feat[o * FEATD + j], s);
    v3[j] = s;
  }
}

// K1: node GEMM on matrix cores (frozen since round 5).
__global__ __launch_bounds__(256) void k_node_mfma(const float* __restrict__ h,
    const float* __restrict__ W_fc, const float* __restrict__ W_attn,
    __half* __restrict__ z, float* __restrict__ s1, float* __restrict__ s2,
    int n_words, int n_nodes) {
  __shared__ float zl[4][16][68];  // +4 pad: conflict-free transpose
  int w = threadIdx.x >> 6, lane = threadIdx.x & 63;
  int nb = blockIdx.x * 64 + w * 16;
  int lrow = lane & 15;
  int lk4 = (lane >> 4) * 4;

  int an = nb + lrow;
  if (an >= n_nodes) an = n_nodes - 1;  // clamp; stores guarded later
  const float* hrow = h + (size_t)an * IN_DIM;

  f32x4 acc[4];
  #pragma unroll
  for (int nt = 0; nt < 4; ++nt) acc[nt] = (f32x4){0.f, 0.f, 0.f, 0.f};

  #pragma unroll
  for (int ks = 0; ks < 8; ++ks) {
    float4 hv = *(const float4*)(hrow + ks * 16 + lk4);
    half4 a;
    a[0] = (_Float16)hv.x; a[1] = (_Float16)hv.y;
    a[2] = (_Float16)hv.z; a[3] = (_Float16)hv.w;
    #pragma unroll
    for (int nt = 0; nt < 4; ++nt) {
      const float* wrow = W_fc + (size_t)(nt * 16 + lrow) * IN_DIM + ks * 16 + lk4;
      float4 wv = *(const float4*)wrow;
      half4 b;
      b[0] = (_Float16)wv.x; b[1] = (_Float16)wv.y;
      b[2] = (_Float16)wv.z; b[3] = (_Float16)wv.w;
      acc[nt] = __builtin_amdgcn_mfma_f32_16x16x16f16(a, b, acc[nt], 0, 0, 0);
    }
  }

  int drow = (lane >> 4) * 4;
  #pragma unroll
  for (int nt = 0; nt < 4; ++nt)
    #pragma unroll
    for (int r = 0; r < 4; ++r)
      zl[w][drow + r][nt * 16 + lrow] = acc[nt][r];

  int node = lane >> 2;    // 0..15
  int chunk = lane & 3;    // 0..3, 16 outs each
  float v[16];
  #pragma unroll
  for (int q = 0; q < 4; ++q) {
    float4 t = *(const float4*)&zl[w][node][chunk * 16 + q * 4];
    v[4 * q + 0] = t.x; v[4 * q + 1] = t.y;
    v[4 * q + 2] = t.z; v[4 * q + 3] = t.w;
  }

  int gn = nb + node;
  bool valid = gn < n_nodes;
  bool isword = gn < n_words;
  const float* wa = W_attn + (isword ? 0 : OUT_DIM) + chunk * 16;
  float p = 0.f;
  #pragma unroll
  for (int t = 0; t < 16; ++t) p = fmaf(v[t], wa[t], p);
  p += __shfl_xor(p, 1);
  p += __shfl_xor(p, 2);

  if (valid && chunk == 0) {
    if (isword) s1[gn] = p; else s2[gn - n_words] = p;
  }
  if (valid && isword) {
    uint32 d[8];
    #pragma unroll
    for (int k = 0; k < 8; ++k) {
      __half2 t = __floats2half2_rn(v[2 * k], v[2 * k + 1]);
      d[k] = *(uint32*)&t;
    }
    uint4* dstp = (uint4*)(z + (size_t)gn * OUT_DIM + chunk * 16);
    dstp[0] = make_uint4(d[0], d[1], d[2], d[3]);
    dstp[1] = make_uint4(d[4], d[5], d[6], d[7]);
  }
}

// K2: histogram of dst + per-edge rank; 2 edges/thread, vectorized.
__global__ __launch_bounds__(256) void k_hist(const int* __restrict__ dst,
                                              uint32* __restrict__ cnt,
                                              uint32* __restrict__ rank, int E) {
  int i = blockIdx.x * 256 + threadIdx.x;
  int e0 = i * 2;
  if (e0 + 1 < E) {
    int2 d2 = *(const int2*)(dst + e0);
    uint32 r0 = atomicAdd(&cnt[d2.x], 1u);
    uint32 r1 = atomicAdd(&cnt[d2.y], 1u);
    *(uint2*)(rank + e0) = make_uint2(r0, r1);
  } else if (e0 < E) {
    rank[e0] = atomicAdd(&cnt[dst[e0]], 1u);
  }
}

// K3: exclusive scan of cnt[0..n) -> off[0..n] (frozen)
__global__ __launch_bounds__(1024) void k_scan(const uint32* __restrict__ cnt,
    uint32* __restrict__ off, int n) {
  __shared__ uint32 part[1024];
  int t = threadIdx.x;
  int CH = (n + 1023) >> 10;
  int base = t * CH;
  uint32 s = 0;
  for (int k = 0; k < CH; ++k) { int i = base + k; if (i < n) s += cnt[i]; }
  part[t] = s;
  __syncthreads();
  uint32 x = s;
  for (int d = 1; d < 1024; d <<= 1) {
    uint32 v = (t >= d) ? part[t - d] : 0u;
    __syncthreads();
    x += v;
    part[t] = x;
    __syncthreads();
  }
  uint32 run = (t > 0) ? part[t - 1] : 0u;
  for (int k = 0; k < CH; ++k) {
    int i = base + k;
    if (i < n) { off[i] = run; run += cnt[i]; }
  }
  if (t == 1023) off[n] = part[1023];
}

// K4: per edge (frozen round-5): f = tfidf.v3 ; e = leaky(...);
//     store {exp(e), src} at off[dst]+rank (no atomics)
__global__ __launch_bounds__(256) void k_edge(const float* __restrict__ tfidf,
    const int* __restrict__ src, const int* __restrict__ dst,
    const float* __restrict__ s1, const float* __restrict__ s2,
    const float* __restrict__ v3, const uint32* __restrict__ off,
    const uint32* __restrict__ rank, float2* __restrict__ pair, int E) {
  int e = blockIdx.x * 256 + threadIdx.x;
  if (e >= E) return;
  const float* row = tfidf + (size_t)e * FEATD;
  float f = 0.f;
  #pragma unroll
  for (int k = 0; k < FEATD / 2; ++k) {
    float2 v = *(const float2*)(row + 2 * k);
    f = fmaf(v.x, v3[2 * k], f);
    f = fmaf(v.y, v3[2 * k + 1], f);
  }
  int sidx = src[e], d = dst[e];
  float ev = s1[sidx] + s2[d] + f;
  ev = ev >= 0.f ? ev : NEG_SLOPE * ev;
  float exv = __expf(ev);
  float2 pr;
  pr.x = exv;
  pr.y = __int_as_float(sidx);
  pair[off[d] + rank[e]] = pr;
}

// K5: one wave per sentence; 8 z-rows per gather instruction; mid loop
// unrolled x2 (16 rows in flight) for better MLP on the 8..63-edge tail.
__global__ __launch_bounds__(256) void k_agg(const __half* __restrict__ z,
    const float2* __restrict__ pair, const uint32* __restrict__ off,
    float* __restrict__ out, int n_sents) {
  int w = threadIdx.x >> 6, lane = threadIdx.x & 63;
  int s = blockIdx.x * 4 + w;
  if (s >= n_sents) return;
  uint32 j0 = off[s], j1 = off[s + 1];
  int sub = lane >> 3;       // 0..7: edge sub-stream
  int d8 = (lane & 7) * 8;   // dim base (8 halves = 16 B)

  float a[8];
  #pragma unroll
  for (int i = 0; i < 8; ++i) a[i] = 0.f;
  float sa = 0.f;

  uint32 b = j0;
  for (; b + 64 <= j1; b += 64) {
    float2 p[8];
    #pragma unroll
    for (int k = 0; k < 8; ++k) p[k] = pair[b + 8 * k + sub];
    uint4 u[8];
    #pragma unroll
    for (int k = 0; k < 8; ++k) {
      uint32 sv = (uint32)__float_as_int(p[k].y);
      u[k] = *(const uint4*)(z + (size_t)sv * OUT_DIM + d8);
    }
    #pragma unroll
    for (int k = 0; k < 8; ++k) {
      float al = p[k].x;
      const __half2* hp = (const __half2*)&u[k];
      #pragma unroll
      for (int q = 0; q < 4; ++q) {
        a[2 * q]     = fmaf(al, __low2float(hp[q]),  a[2 * q]);
        a[2 * q + 1] = fmaf(al, __high2float(hp[q]), a[2 * q + 1]);
      }
      sa += al;
    }
  }
  for (; b + 16 <= j1; b += 16) {
    float2 p0 = pair[b + sub];
    float2 p1 = pair[b + 8 + sub];
    uint32 sv0 = (uint32)__float_as_int(p0.y);
    uint32 sv1 = (uint32)__float_as_int(p1.y);
    uint4 u0 = *(const uint4*)(z + (size_t)sv0 * OUT_DIM + d8);
    uint4 u1 = *(const uint4*)(z + (size_t)sv1 * OUT_DIM + d8);
    const __half2* hp0 = (const __half2*)&u0;
    const __half2* hp1 = (const __half2*)&u1;
    #pragma unroll
    for (int q = 0; q < 4; ++q) {
      a[2 * q]     = fmaf(p0.x, __low2float(hp0[q]),  a[2 * q]);
      a[2 * q + 1] = fmaf(p0.x, __high2float(hp0[q]), a[2 * q + 1]);
      a[2 * q]     = fmaf(p1.x, __low2float(hp1[q]),  a[2 * q]);
      a[2 * q + 1] = fmaf(p1.x, __high2float(hp1[q]), a[2 * q + 1]);
    }
    sa += p0.x + p1.x;
  }
  for (; b + 8 <= j1; b += 8) {
    float2 p = pair[b + sub];
    uint32 sv = (uint32)__float_as_int(p.y);
    uint4 u = *(const uint4*)(z + (size_t)sv * OUT_DIM + d8);
    float al = p.x;
    const __half2* hp = (const __half2*)&u;
    #pragma unroll
    for (int q = 0; q < 4; ++q) {
      a[2 * q]     = fmaf(al, __low2float(hp[q]),  a[2 * q]);
      a[2 * q + 1] = fmaf(al, __high2float(hp[q]), a[2 * q + 1]);
    }
    sa += al;
  }
  if (sub < (int)(j1 - b)) {  // remainder 0..7 edges
    float2 p = pair[b + sub];
    uint32 sv = (uint32)__float_as_int(p.y);
    uint4 u = *(const uint4*)(z + (size_t)sv * OUT_DIM + d8);
    float al = p.x;
    const __half2* hp = (const __half2*)&u;
    #pragma unroll
    for (int q = 0; q < 4; ++q) {
      a[2 * q]     = fmaf(al, __low2float(hp[q]),  a[2 * q]);
      a[2 * q + 1] = fmaf(al, __high2float(hp[q]), a[2 * q + 1]);
    }
    sa += al;
  }

  // reduce across the 8 sub-streams (groups differ in lane bits 3-5)
  #pragma unroll
  for (int i = 0; i < 8; ++i) {
    a[i] += __shfl_xor(a[i], 8);
    a[i] += __shfl_xor(a[i], 16);
    a[i] += __shfl_xor(a[i], 32);
  }
  sa += __shfl_xor(sa, 8); sa += __shfl_xor(sa, 16); sa += __shfl_xor(sa, 32);

  if (sub == 0) {
    float inv = (sa > 0.f) ? (1.f / sa) : 0.f;
    float4 o0, o1;
    o0.x = a[0] * inv; o0.y = a[1] * inv; o0.z = a[2] * inv; o0.w = a[3] * inv;
    o1.x = a[4] * inv; o1.y = a[5] * inv; o1.z = a[6] * inv; o1.w = a[7] * inv;
    float* orow = out + (size_t)s * OUT_DIM + d8;
    *(float4*)orow = o0;
    *(float4*)(orow + 4) = o1;
  }
}

extern "C" void kernel_launch(void* const* d_in, const int* in_sizes, int n_in,
                              void* d_out, int out_size, void* d_ws, size_t ws_size,
                              hipStream_t stream) {
  const float* h      = (const float*)d_in[0];
  const float* tfidf  = (const float*)d_in[1];
  const float* W_fc   = (const float*)d_in[2];
  const float* W_feat = (const float*)d_in[3];
  const float* W_attn = (const float*)d_in[4];
  const int*   src    = (const int*)d_in[5];
  const int*   dst    = (const int*)d_in[6];

  int n_nodes = in_sizes[0] / IN_DIM;   // 220000
  int E       = in_sizes[5];            // 2,000,000
  int n_sents = out_size / OUT_DIM;     // 20000
  int n_words = n_nodes - n_sents;      // 200000
  float* out = (float*)d_out;

  char* ws = (char*)d_ws;
  size_t ofs = 0;
  auto alloc = [&](size_t bytes) -> char* {
    char* p = ws + ofs;
    ofs += (bytes + 255) / 256 * 256;
    return p;
  };
  __half* z      = (__half*)alloc((size_t)n_words * OUT_DIM * 2);
  float*  s1     = (float*)alloc((size_t)n_words * 4);
  float*  s2     = (float*)alloc((size_t)n_sents * 4);
  float2* pair   = (float2*)alloc((size_t)E * 8);
  uint32* rank   = (uint32*)alloc((size_t)E * 4);
  uint32* cnt    = (uint32*)alloc((size_t)n_sents * 4);
  uint32* offs   = (uint32*)alloc((size_t)(n_sents + 1) * 4);
  float*  v3     = (float*)alloc(FEATD * 4);
  (void)ws_size; (void)n_in;

  k_v3zero<<<(n_sents + 255) / 256, 256, 0, stream>>>(W_feat, W_attn, v3, cnt,
                                                      n_sents);
  k_node_mfma<<<(n_nodes + 63) / 64, 256, 0, stream>>>(h, W_fc, W_attn, z, s1,
                                                       s2, n_words, n_nodes);
  k_hist<<<(E / 2 + 255) / 256, 256, 0, stream>>>(dst, cnt, rank, E);
  k_scan<<<1, 1024, 0, stream>>>(cnt, offs, n_sents);
  k_edge<<<(E + 255) / 256, 256, 0, stream>>>(tfidf, src, dst, s1, s2, v3,
                                              offs, rank, pair, E);
  k_agg<<<(n_sents + 3) / 4, 256, 0, stream>>>(z, pair, offs, out, n_sents);
}